// Round 8
// baseline (69.891 us; speedup 1.0000x reference)
//
#include <hip/hip_runtime.h>

#define NBINS 15
#define TPB   128
#define GRID  2560                 // 256 CU x 10 blocks/CU (LDS-bound) = one generation
#define NROWS (2 * NBINS)          // ws rows: [0,15)=sum w*(c-a), [15,30)=count
#define HREC  (NBINS * TPB)        // float2 records [bin][tid] -> 15360 B LDS

// clang native vector type: __builtin_nontemporal_load requires a pointer to
// scalar/native-vector, NOT HIP_vector_type (R7 compile failure).
typedef float f32x4 __attribute__((ext_vector_type(4)));

// ---------------------------------------------------------------------------
// R6 post-mortem: R3/R5/R6 (radically different compute structures) all land
// at 62.7-63.6us with all pipes idle -> the invariant is the memory stream:
// 268 MB read at 4.28 TB/s, split 131 MB HBM (2.1 TB/s) + 137 MB L3. Model:
// the L3-serviced half is the slow path. R8 single-variable test: NON-TEMPORAL
// loads (nt flag) -> no L2/L3 allocation -> the whole stream stays
// HBM-resident across bench iterations and reads at HBM rate.
//
// Identity (R6, verified): per_bin_ece = (sum_c - sum_a)^2 / (count * N), so
// accumulate s1 = sum w*(c-a), s2 = count as float2 b64 records.
// Binning (R6, verified): b = clamp((int)truncf(cm*15), 0, 14), cm=(c<=1)?c:0;
// invalid c -> w=0 contributes (0,0) to bin 0 (harmless).
// Record layout [bin][tid] float2: thread-private 8B slots; bin stride
// TPB*8 = 1024 B == 0 mod 128 -> conflict-free (verified: 0 conflicts).
__device__ __forceinline__ void ece_elem(float c, float a,
                                         float2* __restrict__ slot) {
    float cm = (c <= 1.0f) ? c : 0.0f;
    int b = (int)truncf(cm * 15.0f);
    b = min(max(b, 0), NBINS - 1);
    float w  = (cm > 0.0f) ? 1.0f : 0.0f;
    float wd = w * (c - a);
    float2 r = slot[b * TPB];                     // ds_read_b64
    r.x += wd;
    r.y += w;
    slot[b * TPB] = r;                            // ds_write_b64
}

__device__ __forceinline__ void ece_batch(const f32x4& c0, const f32x4& c1,
                                          const f32x4& a0, const f32x4& a1,
                                          float2* __restrict__ slot) {
    ece_elem(c0.x, a0.x, slot);
    ece_elem(c0.y, a0.y, slot);
    ece_elem(c0.z, a0.z, slot);
    ece_elem(c0.w, a0.w, slot);
    ece_elem(c1.x, a1.x, slot);
    ece_elem(c1.y, a1.y, slot);
    ece_elem(c1.z, a1.z, slot);
    ece_elem(c1.w, a1.w, slot);
}

__global__ __launch_bounds__(TPB, 5) void ece_partial(const float* __restrict__ conf,
                                                      const float* __restrict__ acc,
                                                      float* __restrict__ ws,
                                                      int N, int slotMode) {
    __shared__ float2 hist2[HREC];
    __shared__ float  wred[2][NROWS];
    const int tid  = threadIdx.x;
    const int lane = tid & 63;
    const int wid  = tid >> 6;

    {   // zero-init (b64 stores)
        float2 z = {0.f, 0.f};
        for (int i = tid; i < HREC; i += TPB) hist2[i] = z;
    }
    __syncthreads();

    float2* slot = &hist2[tid];                   // this thread's private column

    const int gid    = blockIdx.x * TPB + tid;
    const int stride = GRID * TPB;
    const f32x4* c4 = (const f32x4*)conf;
    const f32x4* a4 = (const f32x4*)acc;
    const int N8 = N >> 3;

    // 1-deep register prefetch; ALL global reads are non-temporal (nt): the
    // stream must not allocate in L2/L3, so repeat bench iterations keep the
    // data HBM-resident and read at HBM rate instead of the slow L3 path.
    int  p    = gid;
    bool have = p < N8;
    f32x4 c0, c1, a0, a1;
    if (have) {
        c0 = __builtin_nontemporal_load(&c4[2 * p]);
        c1 = __builtin_nontemporal_load(&c4[2 * p + 1]);
        a0 = __builtin_nontemporal_load(&a4[2 * p]);
        a1 = __builtin_nontemporal_load(&a4[2 * p + 1]);
    }
    while (have) {
        const int  pn = p + stride;
        const bool hn = pn < N8;
        const int  pl = hn ? pn : p;              // clamp: always-valid prefetch addr
        f32x4 d0 = __builtin_nontemporal_load(&c4[2 * pl]);
        f32x4 d1 = __builtin_nontemporal_load(&c4[2 * pl + 1]);
        f32x4 e0 = __builtin_nontemporal_load(&a4[2 * pl]);
        f32x4 e1 = __builtin_nontemporal_load(&a4[2 * pl + 1]);

        ece_batch(c0, c1, a0, a1, slot);

        c0 = d0; c1 = d1; a0 = e0; a1 = e1;
        p = pn; have = hn;
    }

    // tail (no-op for N = 2^25)
    for (int i = (N8 << 3) + gid; i < N; i += stride)
        ece_elem(conf[i], acc[i], slot);

    __syncthreads();

    // block reduce: for each bin, butterfly the 128 thread-columns.
    for (int b = 0; b < NBINS; ++b) {
        float2 r = hist2[b * TPB + tid];
        float x = r.x, y = r.y;
        #pragma unroll
        for (int s = 32; s >= 1; s >>= 1) {
            x += __shfl_xor(x, s);
            y += __shfl_xor(y, s);
        }
        if (lane == 0) {
            wred[wid][b]         = x;
            wred[wid][NBINS + b] = y;
        }
    }
    __syncthreads();

    if (tid < NROWS) {
        float S = wred[0][tid] + wred[1][tid];
        if (slotMode) ws[tid * GRID + blockIdx.x] = S;   // block partial, f32
        else          atomicAdd(&ws[tid], S);
    }
}

// ---------------------------------------------------------------------------
// Slot-mode final: reduce 30 rows x GRID columns in f64, then ECE.
// ece = sum_b s1_b^2 / (s2_b * N) over bins with s2_b > 0.
__global__ __launch_bounds__(1024) void ece_final_slots(const float* __restrict__ ws,
                                                        float* __restrict__ out, int N) {
    __shared__ double red[NROWS];
    const int tid = threadIdx.x, lane = tid & 63, w = tid >> 6;
    for (int r = w; r < NROWS; r += 16) {
        double s = 0.0;
        #pragma unroll 4
        for (int it = 0; it < GRID / 64; ++it)
            s += (double)ws[r * GRID + it * 64 + lane];
        #pragma unroll
        for (int sft = 32; sft >= 1; sft >>= 1) s += __shfl_xor(s, sft);
        if (lane == 0) red[r] = s;
    }
    __syncthreads();
    if (w == 0) {
        double per = 0.0;
        if (lane < NBINS) {
            double s1 = red[lane];
            double s2 = red[NBINS + lane];
            per = (s2 > 0.0) ? (s1 * s1) / (s2 * (double)N) : 0.0;
        }
        per += __shfl_down(per, 8);
        per += __shfl_down(per, 4);
        per += __shfl_down(per, 2);
        per += __shfl_down(per, 1);
        if (lane == 0) out[0] = (float)per;
    }
}

// ---------------------------------------------------------------------------
// Atomic-mode fallback (tiny ws): zero + atomic partials + tiny final.
__global__ void ece_zero_ws(float* __restrict__ ws) {
    int t = threadIdx.x;
    if (t < NROWS) ws[t] = 0.0f;
}

__global__ void ece_final_atomic(const float* __restrict__ ws,
                                 float* __restrict__ out, int N) {
    int lane = threadIdx.x;
    double per = 0.0;
    if (lane < NBINS) {
        double s1 = (double)ws[lane];
        double s2 = (double)ws[NBINS + lane];
        per = (s2 > 0.0) ? (s1 * s1) / (s2 * (double)N) : 0.0;
    }
    per += __shfl_down(per, 8);
    per += __shfl_down(per, 4);
    per += __shfl_down(per, 2);
    per += __shfl_down(per, 1);
    if (lane == 0) out[0] = (float)per;
}

// ---------------------------------------------------------------------------
extern "C" void kernel_launch(void* const* d_in, const int* in_sizes, int n_in,
                              void* d_out, int out_size, void* d_ws, size_t ws_size,
                              hipStream_t stream) {
    const float* conf = (const float*)d_in[0];
    const float* acc  = (const float*)d_in[1];
    float* out = (float*)d_out;
    float* ws  = (float*)d_ws;
    const int N = in_sizes[0];

    const size_t need = (size_t)NROWS * GRID * sizeof(float);
    const int slotMode = (ws_size >= need) ? 1 : 0;

    if (!slotMode) ece_zero_ws<<<1, 64, 0, stream>>>(ws);
    ece_partial<<<GRID, TPB, 0, stream>>>(conf, acc, ws, N, slotMode);
    if (slotMode) ece_final_slots<<<1, 1024, 0, stream>>>(ws, out, N);
    else          ece_final_atomic<<<1, 64, 0, stream>>>(ws, out, N);
}

// Round 9
// 59.429 us; speedup vs baseline: 1.1760x; 1.1760x over previous
//
#include <hip/hip_runtime.h>

#define NBINS 15
#define TPB   128
#define GRID  2560                 // 256 CU x 10 blocks/CU (LDS-bound) = one generation
#define NROWS (2 * NBINS)          // ws rows: [0,15)=sum w*(c-a), [15,30)=count
#define HREC  (NBINS * TPB)        // float2 records [bin][tid] -> 15360 B LDS

// ---------------------------------------------------------------------------
// R8 post-mortem: nt-loads (all-HBM) served at the SAME ~4.2 TB/s as the
// mixed HBM+L3 stream -> the 2-stream read-reduce pattern is service-rate
// pinned at ~4.3-4.5 TB/s (R4 3x-outstanding null, R6 2x-waves null; Little's
// law: 20.5 MB in flight / 4.3 TB/s = the observed 4.9us queue latency).
// Partial is at that wall. R9 single-variable: fix the LAST non-memory cost,
// the latency-bound final reduction (was 40 serial dword loads x unroll 4 per
// wave ~5-8us; now 10 fully-unrolled dwordx4 loads per row ~1-2us).
//
// Identity (R6, verified): per_bin_ece = (sum_c - sum_a)^2 / (count * N), so
// accumulate s1 = sum w*(c-a), s2 = count as float2 b64 records.
// Binning (R6, verified): b = clamp((int)truncf(cm*15), 0, 14), cm=(c<=1)?c:0;
// invalid c -> w=0 contributes (0,0) to bin 0 (harmless).
// Record layout [bin][tid] float2: thread-private 8B slots; bin stride
// TPB*8 = 1024 B == 0 mod 128 -> conflict-free (verified: 0 conflicts).
__device__ __forceinline__ void ece_elem(float c, float a,
                                         float2* __restrict__ slot) {
    float cm = (c <= 1.0f) ? c : 0.0f;
    int b = (int)truncf(cm * 15.0f);
    b = min(max(b, 0), NBINS - 1);
    float w  = (cm > 0.0f) ? 1.0f : 0.0f;
    float wd = w * (c - a);
    float2 r = slot[b * TPB];                     // ds_read_b64
    r.x += wd;
    r.y += w;
    slot[b * TPB] = r;                            // ds_write_b64
}

__device__ __forceinline__ void ece_batch(const float4& c0, const float4& c1,
                                          const float4& a0, const float4& a1,
                                          float2* __restrict__ slot) {
    ece_elem(c0.x, a0.x, slot);
    ece_elem(c0.y, a0.y, slot);
    ece_elem(c0.z, a0.z, slot);
    ece_elem(c0.w, a0.w, slot);
    ece_elem(c1.x, a1.x, slot);
    ece_elem(c1.y, a1.y, slot);
    ece_elem(c1.z, a1.z, slot);
    ece_elem(c1.w, a1.w, slot);
}

__global__ __launch_bounds__(TPB, 5) void ece_partial(const float* __restrict__ conf,
                                                      const float* __restrict__ acc,
                                                      float* __restrict__ ws,
                                                      int N, int slotMode) {
    __shared__ float2 hist2[HREC];
    __shared__ float  wred[2][NROWS];
    const int tid  = threadIdx.x;
    const int lane = tid & 63;
    const int wid  = tid >> 6;

    {   // zero-init (b64 stores)
        float2 z = {0.f, 0.f};
        for (int i = tid; i < HREC; i += TPB) hist2[i] = z;
    }
    __syncthreads();

    float2* slot = &hist2[tid];                   // this thread's private column

    const int gid    = blockIdx.x * TPB + tid;
    const int stride = GRID * TPB;
    const float4* c4 = (const float4*)conf;
    const float4* a4 = (const float4*)acc;
    const int N8 = N >> 3;

    // 1-deep register prefetch (R4: deeper is neutral-to-negative; R8: nt
    // hints regress -- normal cached loads are the fastest observed).
    int  p    = gid;
    bool have = p < N8;
    float4 c0, c1, a0, a1;
    if (have) {
        c0 = c4[2 * p]; c1 = c4[2 * p + 1];
        a0 = a4[2 * p]; a1 = a4[2 * p + 1];
    }
    while (have) {
        const int  pn = p + stride;
        const bool hn = pn < N8;
        const int  pl = hn ? pn : p;              // clamp: always-valid prefetch addr
        float4 d0 = c4[2 * pl], d1 = c4[2 * pl + 1];
        float4 e0 = a4[2 * pl], e1 = a4[2 * pl + 1];

        ece_batch(c0, c1, a0, a1, slot);

        c0 = d0; c1 = d1; a0 = e0; a1 = e1;
        p = pn; have = hn;
    }

    // tail (no-op for N = 2^25)
    for (int i = (N8 << 3) + gid; i < N; i += stride)
        ece_elem(conf[i], acc[i], slot);

    __syncthreads();

    // block reduce: for each bin, butterfly the 128 thread-columns.
    for (int b = 0; b < NBINS; ++b) {
        float2 r = hist2[b * TPB + tid];
        float x = r.x, y = r.y;
        #pragma unroll
        for (int s = 32; s >= 1; s >>= 1) {
            x += __shfl_xor(x, s);
            y += __shfl_xor(y, s);
        }
        if (lane == 0) {
            wred[wid][b]         = x;
            wred[wid][NBINS + b] = y;
        }
    }
    __syncthreads();

    if (tid < NROWS) {
        float S = wred[0][tid] + wred[1][tid];
        if (slotMode) ws[tid * GRID + blockIdx.x] = S;   // block partial, f32
        else          atomicAdd(&ws[tid], S);
    }
}

// ---------------------------------------------------------------------------
// Slot-mode final: reduce 30 rows x GRID columns in f64, then ECE.
// ece = sum_b s1_b^2 / (s2_b * N) over bins with s2_b > 0.
// R9: float4 row loads, fully unrolled (10 outstanding dwordx4 per wave)
// instead of 40 serial dwords at unroll 4 -- kills the latency-bound tail.
__global__ __launch_bounds__(1024) void ece_final_slots(const float* __restrict__ ws,
                                                        float* __restrict__ out, int N) {
    __shared__ double red[NROWS];
    const int tid = threadIdx.x, lane = tid & 63, w = tid >> 6;   // 16 waves
    const float4* ws4 = (const float4*)ws;                        // GRID%4==0
    for (int r = w; r < NROWS; r += 16) {
        const float4* row = ws4 + r * (GRID / 4);
        double sx = 0.0, sy = 0.0, sz = 0.0, sw = 0.0;
        #pragma unroll
        for (int it = 0; it < GRID / 256; ++it) {  // 10 iters, all in flight
            float4 v = row[it * 64 + lane];
            sx += (double)v.x; sy += (double)v.y;
            sz += (double)v.z; sw += (double)v.w;
        }
        double s = (sx + sy) + (sz + sw);
        #pragma unroll
        for (int sft = 32; sft >= 1; sft >>= 1) s += __shfl_xor(s, sft);
        if (lane == 0) red[r] = s;
    }
    __syncthreads();
    if (w == 0) {
        double per = 0.0;
        if (lane < NBINS) {
            double s1 = red[lane];
            double s2 = red[NBINS + lane];
            per = (s2 > 0.0) ? (s1 * s1) / (s2 * (double)N) : 0.0;
        }
        per += __shfl_down(per, 8);
        per += __shfl_down(per, 4);
        per += __shfl_down(per, 2);
        per += __shfl_down(per, 1);
        if (lane == 0) out[0] = (float)per;
    }
}

// ---------------------------------------------------------------------------
// Atomic-mode fallback (tiny ws): zero + atomic partials + tiny final.
__global__ void ece_zero_ws(float* __restrict__ ws) {
    int t = threadIdx.x;
    if (t < NROWS) ws[t] = 0.0f;
}

__global__ void ece_final_atomic(const float* __restrict__ ws,
                                 float* __restrict__ out, int N) {
    int lane = threadIdx.x;
    double per = 0.0;
    if (lane < NBINS) {
        double s1 = (double)ws[lane];
        double s2 = (double)ws[NBINS + lane];
        per = (s2 > 0.0) ? (s1 * s1) / (s2 * (double)N) : 0.0;
    }
    per += __shfl_down(per, 8);
    per += __shfl_down(per, 4);
    per += __shfl_down(per, 2);
    per += __shfl_down(per, 1);
    if (lane == 0) out[0] = (float)per;
}

// ---------------------------------------------------------------------------
extern "C" void kernel_launch(void* const* d_in, const int* in_sizes, int n_in,
                              void* d_out, int out_size, void* d_ws, size_t ws_size,
                              hipStream_t stream) {
    const float* conf = (const float*)d_in[0];
    const float* acc  = (const float*)d_in[1];
    float* out = (float*)d_out;
    float* ws  = (float*)d_ws;
    const int N = in_sizes[0];

    const size_t need = (size_t)NROWS * GRID * sizeof(float);
    const int slotMode = (ws_size >= need) ? 1 : 0;

    if (!slotMode) ece_zero_ws<<<1, 64, 0, stream>>>(ws);
    ece_partial<<<GRID, TPB, 0, stream>>>(conf, acc, ws, N, slotMode);
    if (slotMode) ece_final_slots<<<1, 1024, 0, stream>>>(ws, out, N);
    else          ece_final_atomic<<<1, 64, 0, stream>>>(ws, out, N);
}